// Round 1
// baseline (134.060 us; speedup 1.0000x reference)
//
#include <hip/hip_runtime.h>
#include <hip/hip_bf16.h>
#include <stdint.h>

#define BATCH 4096
#define N_TOT 8192
#define D_DIM 256
#define SHIFT 150.0f
#define SQRT2 1.41421356237309515f
#define NBLK 2080  // 64*65/2 triangular 128x128 tiles

typedef __bf16 bf16_t;
typedef bf16_t bf16x8 __attribute__((ext_vector_type(8)));
typedef bf16_t bf16x4 __attribute__((ext_vector_type(4)));
typedef float f32x4 __attribute__((ext_vector_type(4)));

// global -> LDS direct copy, 16B per lane. LDS dest is wave-uniform base;
// HW scatters lane*16B linearly (cannot swizzle the dest -> swizzle the src).
__device__ __forceinline__ void gl_lds16(const void* g, void* l) {
  __builtin_amdgcn_global_load_lds(
      (const __attribute__((address_space(1))) void*)(uintptr_t)g,
      (__attribute__((address_space(3))) void*)(uint32_t)(uintptr_t)l,
      16, 0, 0);
}

// Fused: bf16 convert (x sqrt2), positive-pair dot partials, Zrow+ticket init.
// 1024 blocks x 256 threads; wave w of block b owns row r = b*4+w.
__global__ void k_prep(const float* __restrict__ hi, const float* __restrict__ hj,
                       bf16_t* __restrict__ hb, float* __restrict__ Zrow,
                       float* __restrict__ posPartial, unsigned* __restrict__ ticket) {
  const int wave = threadIdx.x >> 6, lane = threadIdx.x & 63;
  const int r = blockIdx.x * 4 + wave;
  const size_t off = (size_t)r * D_DIM + lane * 4;
  float4 a = *(const float4*)(hi + off);
  float4 b = *(const float4*)(hj + off);

  bf16x4 oa, ob;
  oa[0] = (bf16_t)(a.x * SQRT2); oa[1] = (bf16_t)(a.y * SQRT2);
  oa[2] = (bf16_t)(a.z * SQRT2); oa[3] = (bf16_t)(a.w * SQRT2);
  ob[0] = (bf16_t)(b.x * SQRT2); ob[1] = (bf16_t)(b.y * SQRT2);
  ob[2] = (bf16_t)(b.z * SQRT2); ob[3] = (bf16_t)(b.w * SQRT2);
  *(bf16x4*)(hb + off) = oa;
  *(bf16x4*)(hb + (size_t)BATCH * D_DIM + off) = ob;

  float d = a.x * b.x + a.y * b.y + a.z * b.z + a.w * b.w;
#pragma unroll
  for (int o = 32; o >= 1; o >>= 1) d += __shfl_xor(d, o);
  __shared__ float ps[4];
  if (lane == 0) ps[wave] = d;
  // zero 8 Zrow entries per block (8192 total over 1024 blocks) + ticket
  if (threadIdx.x < 8) Zrow[blockIdx.x * 8 + threadIdx.x] = 0.f;
  if (blockIdx.x == 0 && threadIdx.x == 8) *ticket = 0u;
  __syncthreads();
  if (threadIdx.x == 0) posPartial[blockIdx.x] = ps[0] + ps[1] + ps[2] + ps[3];
}

// Upper-triangular 128x128 tiles of sim = hb.hb^T; fused exp(sim-SHIFT) with
// row-sum AND (off-diag) col-sum accumulation into Zrow. 2080 blocks.
// Pipeline: BK=32 double-buffered LDS (32KB total -> 4 blocks/CU), ONE barrier
// per K-slab, next slab's global_load_lds issued before current slab's MFMA so
// HBM/L2 latency hides under compute (T3-minimum 2-phase, §5.5).
// Last block (device ticket) computes the final loss -> no 3rd kernel.
__global__ __launch_bounds__(256, 4) void k_gemm(const bf16_t* __restrict__ hb,
                                                 float* __restrict__ Zrow,
                                                 const float* __restrict__ posPartial,
                                                 float* __restrict__ out,
                                                 unsigned* __restrict__ ticket) {
  // XCD-aware bijective swizzle: 2080 = 8 XCDs * 260 -> contiguous triangular
  // chunk per XCD keeps the 4MB hb panels L2-resident per XCD.
  const int t0 = blockIdx.x;
  const int t = (t0 & 7) * (NBLK / 8) + (t0 >> 3);
  // decode linear id -> (bi <= bj) triangular pair
  int bj = (int)((sqrtf(8.0f * (float)t + 1.0f) - 1.0f) * 0.5f);
  while ((bj + 1) * (bj + 2) / 2 <= t) ++bj;
  while (bj * (bj + 1) / 2 > t) --bj;
  const int bi = t - bj * (bj + 1) / 2;
  const int rBase = bi * 128;
  const int cBase = bj * 128;
  const bool diag = (bi == bj);

  // [2 buffers][128 rows][32 cols] bf16 = 16 KB each matrix; 32 KB total.
  __shared__ __align__(16) bf16_t As[2][128][32];
  __shared__ __align__(16) bf16_t Bs[2][128][32];
  const int tid = threadIdx.x;
  const int lane = tid & 63;
  const int wave = tid >> 6;

  // ---- staging geometry -------------------------------------------------
  // waves 0,1 -> As row-halves; waves 2,3 -> Bs row-halves.
  // LDS dest is linear: lane -> row = base + (lane>>2), 16B chunk = lane&3.
  // Conflict-free read needs LDS[row][c] = global chunk c ^ ((row>>1)&3)
  // (involution), so pre-swizzle the GLOBAL source chunk per lane.
  const int srow = lane >> 2;                       // row within 16-row group
  const int schunk = (lane & 3) ^ ((lane >> 3) & 3);  // global 16B chunk
  const size_t stageRow = (size_t)((wave < 2 ? rBase : cBase) + (wave & 1) * 64);
  const bf16_t* gsrc = hb + (stageRow + srow) * D_DIM + schunk * 8;
  bf16_t* lbase = (wave < 2) ? &As[0][(wave & 1) * 64][0] : &Bs[0][(wave & 1) * 64][0];

  // one wave stages 64 rows x 64B per slab = 4 issues of 1KB (16 rows each)
  auto STAGE = [&](int b, int kc) {
#pragma unroll
    for (int i = 0; i < 4; ++i)
      gl_lds16(gsrc + (size_t)(i * 16) * D_DIM + kc * 32,
               lbase + b * 4096 + i * 512);
  };

  // ---- fragment geometry ------------------------------------------------
  const int wm = wave >> 1, wn = wave & 1;
  const int quad = lane >> 4, l16 = lane & 15;
  const int co = (quad ^ ((l16 >> 1) & 3)) * 8;  // read-side un-swizzle

  f32x4 acc[4][4];
#pragma unroll
  for (int i = 0; i < 4; ++i)
#pragma unroll
    for (int j = 0; j < 4; ++j) acc[i][j] = (f32x4){0.f, 0.f, 0.f, 0.f};

  STAGE(0, 0);
  __syncthreads();  // drains vmcnt(0): buffer 0 ready

#pragma unroll
  for (int kc = 0; kc < 8; ++kc) {
    const int cur = kc & 1;
    if (kc < 7) STAGE(cur ^ 1, kc + 1);  // loads fly while we compute
    bf16x8 af[4], bfr[4];
#pragma unroll
    for (int mt = 0; mt < 4; ++mt)
      af[mt] = *(const bf16x8*)&As[cur][wm * 64 + mt * 16 + l16][co];
#pragma unroll
    for (int nt = 0; nt < 4; ++nt)
      bfr[nt] = *(const bf16x8*)&Bs[cur][wn * 64 + nt * 16 + l16][co];
#pragma unroll
    for (int mt = 0; mt < 4; ++mt)
#pragma unroll
      for (int nt = 0; nt < 4; ++nt)
        acc[mt][nt] = __builtin_amdgcn_mfma_f32_16x16x32_bf16(af[mt], bfr[nt],
                                                              acc[mt][nt], 0, 0, 0);
    __syncthreads();  // vmcnt(0)+lgkmcnt(0): next buffer landed, cur free
  }

  // epilogue: e = exp(sim - SHIFT); row sums always, col sums for off-diag
  // (symmetry: entry (r,c) also stands in for (c,r)).
  const int rW = rBase + wm * 64 + quad * 4;
  const int cW = cBase + wn * 64 + l16;
  float colAcc[4] = {0.f, 0.f, 0.f, 0.f};
#pragma unroll
  for (int mt = 0; mt < 4; ++mt) {
#pragma unroll
    for (int rg = 0; rg < 4; ++rg) {
      const int rr = rW + mt * 16 + rg;
      float s = 0.f;
#pragma unroll
      for (int nt = 0; nt < 4; ++nt) {
        float e = __expf(acc[mt][nt][rg] - SHIFT);
        if (diag && (rr == cW + nt * 16)) e = 0.f;  // mask self-similarity
        s += e;
        colAcc[nt] += e;
      }
      s += __shfl_xor(s, 1);
      s += __shfl_xor(s, 2);
      s += __shfl_xor(s, 4);
      s += __shfl_xor(s, 8);
      if (l16 == 0) atomicAdd(&Zrow[rr], s);
    }
  }
  if (!diag) {
#pragma unroll
    for (int nt = 0; nt < 4; ++nt) {
      float c = colAcc[nt];
      c += __shfl_xor(c, 16);
      c += __shfl_xor(c, 32);
      if (lane < 16) atomicAdd(&Zrow[cW + nt * 16], c);
    }
  }

  // ---- fused finish: last block computes the loss -----------------------
  __shared__ float redL[4], redP[4];
  __shared__ int lastFlag;
  __syncthreads();  // per-wave vmcnt(0): this block's atomics are complete
  if (tid == 0) {
    __threadfence();
    lastFlag = (atomicAdd(ticket, 1u) == (unsigned)(NBLK - 1)) ? 1 : 0;
  }
  __syncthreads();
  if (lastFlag) {
    __threadfence();
    float sl = 0.f, sp = 0.f;
    for (int i = tid; i < N_TOT; i += 256) {
      float z = __hip_atomic_load(&Zrow[i], __ATOMIC_RELAXED,
                                  __HIP_MEMORY_SCOPE_AGENT);
      sl += __logf(z);
    }
    for (int i = tid; i < 1024; i += 256) sp += posPartial[i];
#pragma unroll
    for (int o = 32; o >= 1; o >>= 1) {
      sl += __shfl_xor(sl, o);
      sp += __shfl_xor(sp, o);
    }
    if (lane == 0) { redL[wave] = sl; redP[wave] = sp; }
    __syncthreads();
    if (tid == 0) {
      float L = redL[0] + redL[1] + redL[2] + redL[3];
      float P = redP[0] + redP[1] + redP[2] + redP[3];
      out[0] = L / (float)N_TOT + SHIFT - P / 2048.0f;
    }
  }
}

extern "C" void kernel_launch(void* const* d_in, const int* in_sizes, int n_in,
                              void* d_out, int out_size, void* d_ws, size_t ws_size,
                              hipStream_t stream) {
  const float* hi = (const float*)d_in[0];
  const float* hj = (const float*)d_in[1];
  float* out = (float*)d_out;

  bf16_t* hb = (bf16_t*)d_ws;                                        // 4 MB
  float* Zrow = (float*)((char*)d_ws + (size_t)N_TOT * D_DIM * 2);   // 32 KB
  float* posPartial = Zrow + N_TOT;                                  // 4 KB
  unsigned* ticket = (unsigned*)(posPartial + 1024);                 // 4 B

  k_prep<<<1024, 256, 0, stream>>>(hi, hj, hb, Zrow, posPartial, ticket);
  k_gemm<<<NBLK, 256, 0, stream>>>(hb, Zrow, posPartial, out, ticket);
}

// Round 2
// 100.719 us; speedup vs baseline: 1.3310x; 1.3310x over previous
//
#include <hip/hip_runtime.h>
#include <hip/hip_bf16.h>
#include <stdint.h>

#define BATCH 4096
#define N_TOT 8192
#define D_DIM 256
#define SHIFT 150.0f
#define SQRT2 1.41421356237309515f

typedef __bf16 bf16_t;
typedef bf16_t bf16x8 __attribute__((ext_vector_type(8)));
typedef bf16_t bf16x4 __attribute__((ext_vector_type(4)));
typedef float f32x4 __attribute__((ext_vector_type(4)));

// global -> LDS direct copy, 16B per lane. LDS dest is wave-uniform base;
// HW scatters lane*16B linearly (cannot swizzle the dest -> swizzle the src).
__device__ __forceinline__ void gl_lds16(const void* g, void* l) {
  __builtin_amdgcn_global_load_lds(
      (const __attribute__((address_space(1))) void*)(uintptr_t)g,
      (__attribute__((address_space(3))) void*)(uint32_t)(uintptr_t)l,
      16, 0, 0);
}

// Fused: bf16 convert (x sqrt2), positive-pair dot partials, Zrow zero-init.
// 1024 blocks x 256 threads; wave w of block b owns row r = b*4+w.
__global__ void k_prep(const float* __restrict__ hi, const float* __restrict__ hj,
                       bf16_t* __restrict__ hb, float* __restrict__ Zrow,
                       float* __restrict__ posPartial) {
  const int wave = threadIdx.x >> 6, lane = threadIdx.x & 63;
  const int r = blockIdx.x * 4 + wave;
  const size_t off = (size_t)r * D_DIM + lane * 4;
  float4 a = *(const float4*)(hi + off);
  float4 b = *(const float4*)(hj + off);

  bf16x4 oa, ob;
  oa[0] = (bf16_t)(a.x * SQRT2); oa[1] = (bf16_t)(a.y * SQRT2);
  oa[2] = (bf16_t)(a.z * SQRT2); oa[3] = (bf16_t)(a.w * SQRT2);
  ob[0] = (bf16_t)(b.x * SQRT2); ob[1] = (bf16_t)(b.y * SQRT2);
  ob[2] = (bf16_t)(b.z * SQRT2); ob[3] = (bf16_t)(b.w * SQRT2);
  *(bf16x4*)(hb + off) = oa;
  *(bf16x4*)(hb + (size_t)BATCH * D_DIM + off) = ob;

  float d = a.x * b.x + a.y * b.y + a.z * b.z + a.w * b.w;
#pragma unroll
  for (int o = 32; o >= 1; o >>= 1) d += __shfl_xor(d, o);
  __shared__ float ps[4];
  if (lane == 0) ps[wave] = d;
  // zero 8 Zrow entries per block (8192 total over 1024 blocks)
  if (threadIdx.x < 8) Zrow[blockIdx.x * 8 + threadIdx.x] = 0.f;
  __syncthreads();
  if (threadIdx.x == 0) posPartial[blockIdx.x] = ps[0] + ps[1] + ps[2] + ps[3];
}

// Upper-triangular 128x128 tiles of sim = hb.hb^T; fused exp(sim-SHIFT) with
// row-sum AND (off-diag) col-sum accumulation into Zrow. 2080 blocks.
// Round-0 verified skeleton (2 barriers per K-slab, single-buffer [128][64]
// LDS, XOR-swizzled staging). ONE change: 8 waves/block (512 thr), per-wave
// tile 32x64, acc[2][4] -> ~80 regs/wave so 3 blocks x 8 waves = 24 waves/CU
// (vs 16) cover the structural barrier drains with more sibling compute.
__global__ __launch_bounds__(512, 6) void k_gemm(const bf16_t* __restrict__ hb,
                                                 float* __restrict__ Zrow) {
  // decode linear block id -> (bi <= bj) triangular pair
  const int t = blockIdx.x;
  int bj = (int)((sqrtf(8.0f * (float)t + 1.0f) - 1.0f) * 0.5f);
  while ((bj + 1) * (bj + 2) / 2 <= t) ++bj;
  while (bj * (bj + 1) / 2 > t) --bj;
  const int bi = t - bj * (bj + 1) / 2;
  const int rBase = bi * 128;
  const int cBase = bj * 128;
  const bool diag = (bi == bj);

  __shared__ __align__(16) bf16_t As[128][64];
  __shared__ __align__(16) bf16_t Bs[128][64];
  const int tid = threadIdx.x;
  const int lane = tid & 63;
  const int wave = tid >> 6;  // 0..7

  // staging: waves 0-3 -> As 32-row quarters; waves 4-7 -> Bs quarters.
  // XOR-swizzle the 16B chunk on the GLOBAL side so LDS[row][c] holds global
  // chunk c ^ (row&7)  (row&7 == lane>>3 here) -> conflict-free frag reads.
  const size_t stageRow = (size_t)((wave < 4 ? rBase : cBase) + (wave & 3) * 32);
  const int c_src = (lane & 7) ^ (lane >> 3);
  const bf16_t* gsrc = hb + stageRow * D_DIM + (size_t)(lane >> 3) * D_DIM + c_src * 8;
  bf16_t* lbase = (wave < 4) ? &As[(wave & 3) * 32][0] : &Bs[(wave & 3) * 32][0];

  const int wm = wave >> 1, wn = wave & 1;  // 4 row-strips x 2 col-strips
  const int quad = lane >> 4, l16 = lane & 15;
  const int sw = l16 & 7;  // read-side un-swizzle key

  f32x4 acc[2][4];
#pragma unroll
  for (int i = 0; i < 2; ++i)
#pragma unroll
    for (int j = 0; j < 4; ++j) acc[i][j] = (f32x4){0.f, 0.f, 0.f, 0.f};

#pragma unroll
  for (int kc = 0; kc < 4; ++kc) {
    __syncthreads();
#pragma unroll
    for (int i = 0; i < 4; ++i)
      gl_lds16(gsrc + (size_t)i * 8 * D_DIM + kc * 64, lbase + i * 8 * 64);
    __syncthreads();
#pragma unroll
    for (int ks = 0; ks < 2; ++ks) {
      bf16x8 af[2], bfr[4];
      const int chunk = ((ks * 4 + quad) ^ sw) * 8;
#pragma unroll
      for (int mt = 0; mt < 2; ++mt)
        af[mt] = *(const bf16x8*)&As[wm * 32 + mt * 16 + l16][chunk];
#pragma unroll
      for (int nt = 0; nt < 4; ++nt)
        bfr[nt] = *(const bf16x8*)&Bs[wn * 64 + nt * 16 + l16][chunk];
#pragma unroll
      for (int mt = 0; mt < 2; ++mt)
#pragma unroll
        for (int nt = 0; nt < 4; ++nt)
          acc[mt][nt] = __builtin_amdgcn_mfma_f32_16x16x32_bf16(af[mt], bfr[nt],
                                                                acc[mt][nt], 0, 0, 0);
    }
  }

  // epilogue: e = exp(sim - SHIFT); row sums always, col sums for off-diag
  // (symmetry: entry (r,c) also stands in for (c,r)).
  const int rW = rBase + wm * 32 + quad * 4;
  const int cW = cBase + wn * 64 + l16;
  float colAcc[4] = {0.f, 0.f, 0.f, 0.f};
#pragma unroll
  for (int mt = 0; mt < 2; ++mt) {
#pragma unroll
    for (int rg = 0; rg < 4; ++rg) {
      const int rr = rW + mt * 16 + rg;
      float s = 0.f;
#pragma unroll
      for (int nt = 0; nt < 4; ++nt) {
        float e = __expf(acc[mt][nt][rg] - SHIFT);
        if (diag && (rr == cW + nt * 16)) e = 0.f;  // mask self-similarity
        s += e;
        colAcc[nt] += e;
      }
      s += __shfl_xor(s, 1);
      s += __shfl_xor(s, 2);
      s += __shfl_xor(s, 4);
      s += __shfl_xor(s, 8);
      if (l16 == 0) atomicAdd(&Zrow[rr], s);
    }
  }
  if (!diag) {
#pragma unroll
    for (int nt = 0; nt < 4; ++nt) {
      float c = colAcc[nt];
      c += __shfl_xor(c, 16);
      c += __shfl_xor(c, 32);
      if (lane < 16) atomicAdd(&Zrow[cW + nt * 16], c);
    }
  }
}

// One block: loss = mean(log Z + SHIFT) - sum(dot)/2048
__global__ void k_finish(const float* __restrict__ Zrow,
                         const float* __restrict__ posPartial,
                         float* __restrict__ out) {
  const int t = threadIdx.x;  // 0..1023
  float4 z0 = *(const float4*)(Zrow + t * 8);
  float4 z1 = *(const float4*)(Zrow + t * 8 + 4);
  float sl = __logf(z0.x) + __logf(z0.y) + __logf(z0.z) + __logf(z0.w) +
             __logf(z1.x) + __logf(z1.y) + __logf(z1.z) + __logf(z1.w);
  float sp = posPartial[t];
#pragma unroll
  for (int o = 32; o >= 1; o >>= 1) {
    sl += __shfl_xor(sl, o);
    sp += __shfl_xor(sp, o);
  }
  __shared__ float pl[16], pp[16];
  const int wave = t >> 6, lane = t & 63;
  if (lane == 0) { pl[wave] = sl; pp[wave] = sp; }
  __syncthreads();
  if (t == 0) {
    float L = 0.f, P = 0.f;
    for (int i = 0; i < 16; ++i) { L += pl[i]; P += pp[i]; }
    out[0] = L / (float)N_TOT + SHIFT - P / 2048.0f;
  }
}

extern "C" void kernel_launch(void* const* d_in, const int* in_sizes, int n_in,
                              void* d_out, int out_size, void* d_ws, size_t ws_size,
                              hipStream_t stream) {
  const float* hi = (const float*)d_in[0];
  const float* hj = (const float*)d_in[1];
  float* out = (float*)d_out;

  bf16_t* hb = (bf16_t*)d_ws;                                        // 4 MB
  float* Zrow = (float*)((char*)d_ws + (size_t)N_TOT * D_DIM * 2);   // 32 KB
  float* posPartial = Zrow + N_TOT;                                  // 4 KB

  k_prep<<<1024, 256, 0, stream>>>(hi, hj, hb, Zrow, posPartial);
  k_gemm<<<2080, 512, 0, stream>>>(hb, Zrow);
  k_finish<<<1, 1024, 0, stream>>>(Zrow, posPartial, out);
}